// Round 1
// baseline (35.797 us; speedup 1.0000x reference)
//
#include <hip/hip_runtime.h>
#include <math.h>

// Problem: B=256, D=512, H=512.
// Separable head: pre[i,j,h] = A'[j,h] + C[i,h]
//   A'[j,h] = emb[j,:] @ W1[0:512, h] + b1[h]
//   C [i,h] = emb[i,:] @ W1[512:1024, h]
// loss[i,j] = BCE(labels[i]==labels[j], sigmoid(sum_h relu(A'+C)*w2[h] + b2))

#define B 256
#define D 512
#define H 512

// ---------------- Kernel 1: A' and C (fp32 GEMM, 8 rows per block) ---------
// grid: (2 col-halves, 32 row-groups, 2 matrices), block: 256
__global__ __launch_bounds__(256) void head_gemm(
    const float* __restrict__ emb, const float* __restrict__ W1,
    const float* __restrict__ b1, float* __restrict__ A, float* __restrict__ C) {
    __shared__ float sE[8 * D];  // 16 KiB: 8 emb rows (contiguous in global)

    const int z  = blockIdx.z;              // 0: A' (top half of W1), 1: C
    const int r0 = blockIdx.y * 8;          // first emb row of this block
    const int h  = blockIdx.x * 256 + threadIdx.x;  // output column

    // 8 rows x 512 = 4096 floats, contiguous -> straight float4 copy
    const float4* src = (const float4*)(emb + (size_t)r0 * D);
    for (int idx = threadIdx.x; idx < (8 * D) / 4; idx += 256)
        ((float4*)sE)[idx] = src[idx];
    __syncthreads();

    float acc[8];
    const float binit = z ? 0.0f : b1[h];
#pragma unroll
    for (int r = 0; r < 8; ++r) acc[r] = binit;

    const float* w = W1 + (size_t)(z * D) * H + h;  // column h, stride H per d

#pragma unroll 2
    for (int d = 0; d < D; d += 4) {
        const float w0 = w[(size_t)(d + 0) * H];
        const float w1v = w[(size_t)(d + 1) * H];
        const float w2v = w[(size_t)(d + 2) * H];
        const float w3v = w[(size_t)(d + 3) * H];
#pragma unroll
        for (int r = 0; r < 8; ++r) {
            float4 e = *(const float4*)&sE[r * D + d];  // wave-uniform -> broadcast
            acc[r] = fmaf(e.x, w0, acc[r]);
            acc[r] = fmaf(e.y, w1v, acc[r]);
            acc[r] = fmaf(e.z, w2v, acc[r]);
            acc[r] = fmaf(e.w, w3v, acc[r]);
        }
    }

    float* dst = z ? C : A;
#pragma unroll
    for (int r = 0; r < 8; ++r) dst[(size_t)(r0 + r) * H + h] = acc[r];
}

// ---------------- Kernel 2: pairwise relu-dot + BCE ------------------------
// grid: (16,16) pair tiles of 16x16, block: 256 (one pair per thread)
#define PADH 516  // 512 + 4 floats: row-start bank = 4*r mod 32 -> 2-way only (free)

__global__ __launch_bounds__(256) void pair_loss(
    const float* __restrict__ A, const float* __restrict__ C,
    const float* __restrict__ w2, const float* __restrict__ b2,
    const int* __restrict__ labels, float* __restrict__ out) {
    __shared__ float sA[16][PADH];
    __shared__ float sC[16][PADH];
    __shared__ float sW[H];

    const int j0 = blockIdx.x * 16;
    const int i0 = blockIdx.y * 16;
    const int tid = threadIdx.x;

    // Stage 16 rows of A' (j-tile) and 16 rows of C (i-tile); rows contiguous.
    for (int idx = tid; idx < 16 * (H / 4); idx += 256) {
        const int r = idx >> 7;          // H/4 = 128 float4 per row
        const int c4 = idx & 127;
        float4 va = ((const float4*)(A + (size_t)(j0 + r) * H))[c4];
        *(float4*)&sA[r][c4 * 4] = va;
        float4 vc = ((const float4*)(C + (size_t)(i0 + r) * H))[c4];
        *(float4*)&sC[r][c4 * 4] = vc;
    }
    for (int idx = tid; idx < H; idx += 256) sW[idx] = w2[idx];
    __syncthreads();

    const int tx = tid & 15;   // j within tile
    const int ty = tid >> 4;   // i within tile

    float s = 0.0f;
#pragma unroll 8
    for (int h = 0; h < H; h += 4) {
        float4 a = *(const float4*)&sA[tx][h];
        float4 c = *(const float4*)&sC[ty][h];
        float4 w = *(const float4*)&sW[h];
        s = fmaf(fmaxf(a.x + c.x, 0.0f), w.x, s);
        s = fmaf(fmaxf(a.y + c.y, 0.0f), w.y, s);
        s = fmaf(fmaxf(a.z + c.z, 0.0f), w.z, s);
        s = fmaf(fmaxf(a.w + c.w, 0.0f), w.w, s);
    }

    const float z = s + b2[0];
    float p = 1.0f / (1.0f + expf(-z));
    p = fminf(fmaxf(p, 1e-7f), 1.0f - 1e-7f);

    const int i = i0 + ty;
    const int j = j0 + tx;
    const float t = (labels[i] == labels[j]) ? 1.0f : 0.0f;
    const float loss = -(t * logf(p) + (1.0f - t) * log1pf(-p));
    out[(size_t)i * B + j] = loss;
}

extern "C" void kernel_launch(void* const* d_in, const int* in_sizes, int n_in,
                              void* d_out, int out_size, void* d_ws, size_t ws_size,
                              hipStream_t stream) {
    const float* emb    = (const float*)d_in[0];
    const int*   labels = (const int*)d_in[1];
    const float* W1     = (const float*)d_in[2];
    const float* b1     = (const float*)d_in[3];
    const float* W2     = (const float*)d_in[4];
    const float* b2     = (const float*)d_in[5];
    float* out = (float*)d_out;

    float* A = (float*)d_ws;                 // 256*512 floats
    float* C = A + (size_t)B * H;            // 256*512 floats (total 1 MiB)

    dim3 g1(2, 32, 2);
    head_gemm<<<g1, 256, 0, stream>>>(emb, W1, b1, A, C);

    dim3 g2(16, 16);
    pair_loss<<<g2, 256, 0, stream>>>(A, C, W2, b2, labels, out);
}